// Round 4
// baseline (194.543 us; speedup 1.0000x reference)
//
#include <hip/hip_runtime.h>
#include <hip/hip_bf16.h>

// Problem constants
#define BB 128
#define TT 384
#define CC 256
#define HH 4
#define KVH 2
#define QKVW 512
#define MROWS (BB * TT)   // 49152

#define CVT_BLOCKS 6144   // x fp32->bf16: 12.58M elems, 8/thread

typedef __attribute__((ext_vector_type(8))) short short8;
typedef __attribute__((ext_vector_type(4))) float float4v;

__device__ __forceinline__ unsigned short f2b(float f) {
    union { float f; unsigned u; } v; v.f = f;
    unsigned u = v.u;
    unsigned r = (u + 0x7fffu + ((u >> 16) & 1u)) >> 16;
    return (unsigned short)r;
}
__device__ __forceinline__ float4v mfma16(short8 a, short8 b, float4v c) {
    return __builtin_amdgcn_mfma_f32_16x16x32_bf16(a, b, c, 0, 0, 0);
}
// Async global->LDS, 16B per lane. LDS dest = wave-uniform ptr + lane*16.
__device__ __forceinline__ void g2lds16(const void* g, void* l) {
    __builtin_amdgcn_global_load_lds(
        (const __attribute__((address_space(1))) unsigned int*)g,
        (__attribute__((address_space(3))) unsigned int*)l, 16, 0, 0);
}
// Pack high-halves of (a,b) with +0x8000 rounding into one dword [b_hi:a_hi].
__device__ __forceinline__ unsigned pk2bf(float a, float b) {
    union { float f; unsigned u; } x, y; x.f = a; y.f = b;
    return __builtin_amdgcn_perm(y.u + 0x8000u, x.u + 0x8000u, 0x07060302u);
}

// ---------------------------------------------------------------------------
// Prep (fused): [blocks 0..CVT_BLOCKS) convert x fp32->bf16 (8 elems/thread);
// remaining blocks pack W^T bf16 + fp64-accurate RoPE tables.
// ---------------------------------------------------------------------------
__global__ void prep_kernel(const float* __restrict__ x, unsigned short* __restrict__ xb,
                            const float* __restrict__ Wq, const float* __restrict__ Wk,
                            const float* __restrict__ Wv, const float* __restrict__ Wo,
                            unsigned short* __restrict__ WqkvT, unsigned short* __restrict__ WoT,
                            float* __restrict__ cosT, float* __restrict__ sinT) {
    if (blockIdx.x < CVT_BLOCKS) {
        size_t e = ((size_t)blockIdx.x * 256 + threadIdx.x) * 8;
        const float4* p = (const float4*)(x + e);
        float4 v0 = p[0], v1 = p[1];
        short8 w;
        w[0]=(short)f2b(v0.x); w[1]=(short)f2b(v0.y); w[2]=(short)f2b(v0.z); w[3]=(short)f2b(v0.w);
        w[4]=(short)f2b(v1.x); w[5]=(short)f2b(v1.y); w[6]=(short)f2b(v1.z); w[7]=(short)f2b(v1.w);
        *(short8*)(xb + e) = w;
        return;
    }
    int idx = (blockIdx.x - CVT_BLOCKS) * 256 + threadIdx.x;
    const int N1 = QKVW * CC;          // 131072
    const int N2 = N1 + CC * CC;       // +65536
    const int N3 = N2 + TT * 32;       // +12288
    if (idx < N1) {
        int n = idx >> 8, k = idx & 255;
        float w;
        if (n < 256)      w = Wq[k * 256 + n];
        else if (n < 384) w = Wk[k * 128 + (n - 256)];
        else              w = Wv[k * 128 + (n - 384)];
        WqkvT[n * 256 + k] = f2b(w);
    } else if (idx < N2) {
        int i = idx - N1; int n = i >> 8, k = i & 255;
        WoT[n * 256 + k] = f2b(Wo[k * 256 + n]);
    } else if (idx < N3) {
        int i = idx - N2;
        int t = i >> 5, f = i & 31;
        double invf = exp2(-(double)f / 32.0 * 13.287712379549449);  // 10000^(-f/32)
        double ang = (double)t * invf;
        cosT[t * 32 + f] = (float)cos(ang);
        sinT[t * 32 + f] = (float)sin(ang);
    }
}

// ---------------------------------------------------------------------------
// GEMM1 (m97-style): qkv = xb @ [Wq|Wk|Wv], async LDS staging, fused RoPE +
// layout epilogue. XCD swizzle: the 4 nt-variants of one mt share an XCD.
// Emits: Qr [b][h][t][64] (*0.125*log2e), Kr [b][g][s][64],
//        Vt [b][g][s/64][d][sigma(s%64)]  (sigma = attn's P-column permute).
// ---------------------------------------------------------------------------
__global__ __launch_bounds__(256) void gemm_qkv_kernel(
    const unsigned short* __restrict__ A, const unsigned short* __restrict__ BT,
    unsigned short* __restrict__ Qr, unsigned short* __restrict__ Kr,
    unsigned short* __restrict__ Vt,
    const float* __restrict__ cosT, const float* __restrict__ sinT)
{
    __shared__ __align__(16) unsigned short As[128 * 32];
    __shared__ __align__(16) unsigned short Bs[128 * 32];
    const int tid  = threadIdx.x;
    const int lane = tid & 63;
    const int quad = lane >> 4, l16 = lane & 15;
    const int wave = tid >> 6;
    // XCD-locality swizzle: mt = 8*(bid>>5) + (bid&7); nt = (bid>>3)&3
    const int mt = ((blockIdx.x >> 5) << 3) | (blockIdx.x & 7);
    const int nt = (blockIdx.x >> 3) & 3;
    const int mbase = mt * 128, nbase = nt * 128;
    const int wmb = (wave >> 1) * 64, wnb = (wave & 1) * 64;

    float4v acc[4][4] = {};
    const int r0 = tid >> 2, kc = (tid & 3) * 8;
    const int ldsW = (tid & ~63) * 16;
    const unsigned short* gA0 = A  + (size_t)(mbase + r0) * CC + kc;
    const unsigned short* gB0 = BT + (size_t)(nbase + r0) * CC + kc;

    for (int kt = 0; kt < CC; kt += 32) {
        __syncthreads();
        g2lds16(gA0 + kt,                  (char*)As + ldsW);
        g2lds16(gA0 + kt + (size_t)64*CC,  (char*)As + 4096 + ldsW);
        g2lds16(gB0 + kt,                  (char*)Bs + ldsW);
        g2lds16(gB0 + kt + (size_t)64*CC,  (char*)Bs + 4096 + ldsW);
        __syncthreads();

        short8 af[4], bf_[4];
        #pragma unroll
        for (int i = 0; i < 4; i++)
            af[i] = *(const short8*)&As[(wmb + i * 16 + l16) * 32 + quad * 8];
        #pragma unroll
        for (int i = 0; i < 4; i++)
            bf_[i] = *(const short8*)&Bs[(wnb + i * 16 + l16) * 32 + quad * 8];
        #pragma unroll
        for (int i = 0; i < 4; i++)
            #pragma unroll
            for (int j = 0; j < 4; j++)
                acc[i][j] = mfma16(af[i], bf_[j], acc[i][j]);
    }

    const int gn0 = nbase + wnb;
    const int gm0 = mbase + wmb;
    if (gn0 < 384) {
        const bool isq = (gn0 < 256);
        const int  hh  = isq ? (gn0 >> 6) : ((gn0 - 256) >> 6);
        const float qs = isq ? 0.18033688011112042f : 1.0f;   // 0.125 * log2(e)
        #pragma unroll
        for (int i = 0; i < 4; i++) {
            #pragma unroll
            for (int r = 0; r < 4; r++) {
                int gm = gm0 + i * 16 + quad * 4 + r;
                int b = gm / TT, t = gm - b * TT;
                unsigned short* dst = isq
                    ? (Qr + (((size_t)b * HH  + hh) * TT + t) * 64)
                    : (Kr + (((size_t)b * KVH + hh) * TT + t) * 64);
                #pragma unroll
                for (int j = 0; j < 2; j++) {
                    int f = j * 16 + l16;
                    float cs = cosT[t * 32 + f], sn = sinT[t * 32 + f];
                    float a  = acc[i][j][r],     c2 = acc[i][j + 2][r];
                    dst[f]      = f2b((a * cs - c2 * sn) * qs);
                    dst[f + 32] = f2b((c2 * cs + a * sn) * qs);
                }
            }
        }
    } else {
        const int g = (gn0 - 384) >> 6;
        #pragma unroll
        for (int i = 0; i < 4; i++) {
            #pragma unroll
            for (int r = 0; r < 4; r++) {
                int gm = gm0 + i * 16 + quad * 4 + r;
                int b = gm / TT, s = gm - b * TT;
                int s6 = s & 63;
                int sig = (s6 & 15) * 4 + (s6 >> 4);   // key permutation
                unsigned short* dst = Vt + (((size_t)b * KVH + g) * 6 + (s >> 6)) * 4096 + sig;
                #pragma unroll
                for (int j = 0; j < 4; j++)
                    dst[(j * 16 + l16) * 64] = f2b(acc[i][j][r]);
            }
        }
    }
}

// ---------------------------------------------------------------------------
// GEMM2 (m97-style): out = y @ Wo, out fp32. XCD swizzle on (mt,nt).
// ---------------------------------------------------------------------------
__global__ __launch_bounds__(256) void gemm_out_kernel(
    const unsigned short* __restrict__ A, const unsigned short* __restrict__ BT,
    float* __restrict__ C)
{
    __shared__ __align__(16) unsigned short As[128 * 32];
    __shared__ __align__(16) unsigned short Bs[128 * 32];
    const int tid  = threadIdx.x;
    const int lane = tid & 63;
    const int quad = lane >> 4, l16 = lane & 15;
    const int wave = tid >> 6;
    const int mt = ((blockIdx.x >> 4) << 3) | (blockIdx.x & 7);
    const int nt = (blockIdx.x >> 3) & 1;
    const int mbase = mt * 128, nbase = nt * 128;
    const int wmb = (wave >> 1) * 64, wnb = (wave & 1) * 64;

    float4v acc[4][4] = {};
    const int r0 = tid >> 2, kc = (tid & 3) * 8;
    const int ldsW = (tid & ~63) * 16;
    const unsigned short* gA0 = A  + (size_t)(mbase + r0) * CC + kc;
    const unsigned short* gB0 = BT + (size_t)(nbase + r0) * CC + kc;

    for (int kt = 0; kt < CC; kt += 32) {
        __syncthreads();
        g2lds16(gA0 + kt,                  (char*)As + ldsW);
        g2lds16(gA0 + kt + (size_t)64*CC,  (char*)As + 4096 + ldsW);
        g2lds16(gB0 + kt,                  (char*)Bs + ldsW);
        g2lds16(gB0 + kt + (size_t)64*CC,  (char*)Bs + 4096 + ldsW);
        __syncthreads();

        short8 af[4], bf_[4];
        #pragma unroll
        for (int i = 0; i < 4; i++)
            af[i] = *(const short8*)&As[(wmb + i * 16 + l16) * 32 + quad * 8];
        #pragma unroll
        for (int i = 0; i < 4; i++)
            bf_[i] = *(const short8*)&Bs[(wnb + i * 16 + l16) * 32 + quad * 8];
        #pragma unroll
        for (int i = 0; i < 4; i++)
            #pragma unroll
            for (int j = 0; j < 4; j++)
                acc[i][j] = mfma16(af[i], bf_[j], acc[i][j]);
    }
    #pragma unroll
    for (int i = 0; i < 4; i++)
        #pragma unroll
        for (int j = 0; j < 4; j++)
            #pragma unroll
            for (int r = 0; r < 4; r++)
                C[(size_t)(mbase + wmb + i * 16 + quad * 4 + r) * CC + nbase + wnb + j * 16 + l16]
                    = acc[i][j][r];
}

// ---------------------------------------------------------------------------
// Attention v3: block = (b, g, p) handles q-tiles {p, 5-p} -> uniform 7
// tile-computes per block; 768 blocks = 3/CU fully resident. K/V double-
// buffered (one barrier per k-iter; prefetch issued post-barrier overlaps
// compute). P stored via key-permutation sigma: each lane's 4 score columns
// are contiguous -> ds_write_b64 (+ v_perm packing). Fixed-max softmax,
// row-sums via ones-MFMA. XCD swizzle co-locates a (b,g)'s 3 blocks.
// ---------------------------------------------------------------------------
__global__ __launch_bounds__(256, 3) void attn_kernel(
    const unsigned short* __restrict__ Qr, const unsigned short* __restrict__ Kr,
    const unsigned short* __restrict__ Vt, unsigned short* __restrict__ y)
{
    __shared__ __align__(16) unsigned short Ks[2][64 * 64];  // 2 x 8 KB, XOR-swizzled [s][d]
    __shared__ __align__(16) unsigned short Vs[2][64 * 64];  // 2 x 8 KB, XOR-swizzled [d][sigma]
    __shared__ __align__(16) unsigned short Ps[4][32 * 64];  // per-wave [q][sigma], row-XOR

    const int tid  = threadIdx.x;
    const int lane = tid & 63;
    const int wave = tid >> 6;
    const int quad = lane >> 4, l16 = lane & 15;

    // decode with XCD co-location: all 3 p-blocks of (b,g) share bid&7
    const int xc  = blockIdx.x & 7;
    const int jj  = blockIdx.x >> 3;        // 0..95
    const int p   = jj % 3;
    const int bg  = (jj / 3) * 8 + xc;      // 0..255
    const int g   = bg & 1, b = bg >> 1;
    const int h   = g * 2 + (wave >> 1);
    const int qtA = 5 - p, qtB = p;
    const int qbA = qtA * 64 + (wave & 1) * 32;
    const int qbB = qtB * 64 + (wave & 1) * 32;

    // Q fragments for both tiles: [tile][mi][half]
    short8 qf[2][2][2];
    #pragma unroll
    for (int t = 0; t < 2; t++) {
        int qb = t ? qbB : qbA;
        #pragma unroll
        for (int mi = 0; mi < 2; mi++)
            #pragma unroll
            for (int half = 0; half < 2; half++)
                qf[t][mi][half] = *(const short8*)(Qr
                    + (((size_t)b * HH + h) * TT + qb + mi * 16 + l16) * 64
                    + half * 32 + quad * 8);
    }

    float4v acc[2][2][4] = {};
    float4v accl[2][2]   = {};
    short8 ones;
    #pragma unroll
    for (int j = 0; j < 8; j++) ones[j] = (short)0x3F80;

    const unsigned short* Kbase = Kr + ((size_t)b * KVH + g) * TT * 64;
    const unsigned short* Vbase = Vt + ((size_t)b * KVH + g) * 6 * 4096;
    char* Pw = (char*)&Ps[wave][0];
    const int ldsWave = (tid & ~63) * 16;
    // XOR-swizzled staging source offsets (elements) for chunk groups 0/1
    int gc0, gc1;
    { int L0 = tid;       gc0 = ((L0 & ~7) | ((L0 & 7) ^ ((L0 >> 3) & 7))) * 8;
      int L1 = 256 + tid; gc1 = ((L1 & ~7) | ((L1 & 7) ^ ((L1 >> 3) & 7))) * 8; }

    auto stage = [&](int bi, int kt) {
        const unsigned short* kB = Kbase + (size_t)kt * 4096;
        const unsigned short* vB = Vbase + (size_t)kt * 4096;
        g2lds16(kB + gc0, (char*)&Ks[bi][0] + ldsWave);
        g2lds16(kB + gc1, (char*)&Ks[bi][0] + 4096 + ldsWave);
        g2lds16(vB + gc0, (char*)&Vs[bi][0] + ldsWave);
        g2lds16(vB + gc1, (char*)&Vs[bi][0] + 4096 + ldsWave);
    };

    auto computeTile = [&](int t, const unsigned short* Kc, const unsigned short* Vc,
                           bool domask) {
        // S = Q . K^T (16 MFMAs)
        float4v s_[2][4];
        #pragma unroll
        for (int js = 0; js < 4; js++) {
            int srow = js * 16 + l16, sw = srow & 7;
            short8 kb0 = *(const short8*)((const char*)Kc + srow * 128 + ((quad ^ sw) * 16));
            short8 kb1 = *(const short8*)((const char*)Kc + srow * 128 + (((4 + quad) ^ sw) * 16));
            #pragma unroll
            for (int mi = 0; mi < 2; mi++) {
                float4v z = {};
                z = mfma16(qf[t][mi][0], kb0, z);
                s_[mi][js] = mfma16(qf[t][mi][1], kb1, z);
            }
        }
        if (domask) {
            #pragma unroll
            for (int mi = 0; mi < 2; mi++)
                #pragma unroll
                for (int js = 0; js < 4; js++) {
                    int coll = js * 16 + l16;
                    #pragma unroll
                    for (int r = 0; r < 4; r++) {
                        int rowl = (wave & 1) * 32 + mi * 16 + quad * 4 + r;
                        if (coll > rowl) s_[mi][js][r] = -1e30f;
                    }
                }
        }
        // P = exp2(s), packed b64 store: lane's 4 cols are contiguous under sigma
        #pragma unroll
        for (int mi = 0; mi < 2; mi++)
            #pragma unroll
            for (int r = 0; r < 4; r++) {
                float e0 = __builtin_amdgcn_exp2f(s_[mi][0][r]);
                float e1 = __builtin_amdgcn_exp2f(s_[mi][1][r]);
                float e2 = __builtin_amdgcn_exp2f(s_[mi][2][r]);
                float e3 = __builtin_amdgcn_exp2f(s_[mi][3][r]);
                unsigned long long d =
                    (unsigned long long)pk2bf(e0, e1) |
                    ((unsigned long long)pk2bf(e2, e3) << 32);
                int rho = mi * 16 + quad * 4 + r;
                int ch  = l16 ^ (((quad * 4 + r) & 7) << 1);
                *(unsigned long long*)(Pw + rho * 128 + ch * 8) = d;
            }
        // P A-frags (b128) + PV (16 MFMAs) + row-sums (4 MFMAs)
        short8 pa[2][2];
        #pragma unroll
        for (int mi = 0; mi < 2; mi++)
            #pragma unroll
            for (int half = 0; half < 2; half++) {
                int chp = (2 * (half * 4 + quad)) ^ ((l16 & 7) << 1);
                pa[mi][half] = *(const short8*)(Pw + (mi * 16 + l16) * 128 + chp * 8);
            }
        #pragma unroll
        for (int dj = 0; dj < 4; dj++) {
            int vrow = dj * 16 + l16, sw = vrow & 7;
            short8 vb0 = *(const short8*)((const char*)Vc + vrow * 128 + ((quad ^ sw) * 16));
            short8 vb1 = *(const short8*)((const char*)Vc + vrow * 128 + (((4 + quad) ^ sw) * 16));
            #pragma unroll
            for (int mi = 0; mi < 2; mi++) {
                acc[t][mi][dj] = mfma16(pa[mi][0], vb0, acc[t][mi][dj]);
                acc[t][mi][dj] = mfma16(pa[mi][1], vb1, acc[t][mi][dj]);
            }
        }
        #pragma unroll
        for (int mi = 0; mi < 2; mi++) {
            accl[t][mi] = mfma16(pa[mi][0], ones, accl[t][mi]);
            accl[t][mi] = mfma16(pa[mi][1], ones, accl[t][mi]);
        }
    };

    stage(0, 0);
    for (int kt = 0; kt <= qtA; kt++) {
        __syncthreads();                       // drains staging of kt; fences prior readers
        if (kt < qtA) stage((kt + 1) & 1, kt + 1);   // prefetch overlaps compute below
        const unsigned short* Kc = &Ks[kt & 1][0];
        const unsigned short* Vc = &Vs[kt & 1][0];
        computeTile(0, Kc, Vc, kt == qtA);
        if (kt <= qtB) computeTile(1, Kc, Vc, kt == qtB);
    }

    // epilogue: y[b][t][h*64+d] = acc / l   (both tiles)
    #pragma unroll
    for (int t = 0; t < 2; t++) {
        int qb = t ? qbB : qbA;
        #pragma unroll
        for (int mi = 0; mi < 2; mi++) {
            float rinv[4];
            #pragma unroll
            for (int r = 0; r < 4; r++) rinv[r] = 1.0f / accl[t][mi][r];
            #pragma unroll
            for (int dj = 0; dj < 4; dj++)
                #pragma unroll
                for (int r = 0; r < 4; r++) {
                    int tt = qb + mi * 16 + quad * 4 + r;
                    y[((size_t)b * TT + tt) * CC + h * 64 + dj * 16 + l16]
                        = f2b(acc[t][mi][dj][r] * rinv[r]);
                }
        }
    }
}

// ---------------------------------------------------------------------------
extern "C" void kernel_launch(void* const* d_in, const int* in_sizes, int n_in,
                              void* d_out, int out_size, void* d_ws, size_t ws_size,
                              hipStream_t stream) {
    const float* x  = (const float*)d_in[0];
    const float* Wq = (const float*)d_in[1];
    const float* Wk = (const float*)d_in[2];
    const float* Wv = (const float*)d_in[3];
    const float* Wo = (const float*)d_in[4];
    float* out = (float*)d_out;

    char* ws = (char*)d_ws;
    size_t off = 0;
    unsigned short* xb = (unsigned short*)(ws + off); off += (size_t)MROWS * CC * 2;
    unsigned short* Qr = (unsigned short*)(ws + off); off += (size_t)BB * HH  * TT * 64 * 2;
    unsigned short* Kr = (unsigned short*)(ws + off); off += (size_t)BB * KVH * TT * 64 * 2;
    unsigned short* Vt = (unsigned short*)(ws + off); off += (size_t)BB * KVH * TT * 64 * 2;
    unsigned short* y  = (unsigned short*)(ws + off); off += (size_t)MROWS * CC * 2;
    unsigned short* WqkvT = (unsigned short*)(ws + off); off += (size_t)QKVW * CC * 2;
    unsigned short* WoT   = (unsigned short*)(ws + off); off += (size_t)CC * CC * 2;
    float* cosT = (float*)(ws + off); off += (size_t)TT * 32 * 4;
    float* sinT = (float*)(ws + off); off += (size_t)TT * 32 * 4;

    prep_kernel<<<CVT_BLOCKS + 816, 256, 0, stream>>>(x, xb, Wq, Wk, Wv, Wo,
                                                      WqkvT, WoT, cosT, sinT);
    gemm_qkv_kernel<<<(MROWS / 128) * 4, 256, 0, stream>>>(xb, WqkvT, Qr, Kr, Vt, cosT, sinT);
    attn_kernel<<<BB * KVH * 3, 256, 0, stream>>>(Qr, Kr, Vt, y);
    gemm_out_kernel<<<(MROWS / 128) * 2, 256, 0, stream>>>(y, WoT, out);
}

// Round 5
// 160.744 us; speedup vs baseline: 1.2103x; 1.2103x over previous
//
#include <hip/hip_runtime.h>
#include <hip/hip_bf16.h>

// Problem constants
#define BB 128
#define TT 384
#define CC 256
#define HH 4
#define KVH 2
#define QKVW 512
#define MROWS (BB * TT)   // 49152

#define CVT_BLOCKS 6144   // x fp32->bf16: 12.58M elems, 8/thread

typedef __attribute__((ext_vector_type(8))) short short8;
typedef __attribute__((ext_vector_type(4))) float float4v;

__device__ __forceinline__ unsigned short f2b(float f) {
    union { float f; unsigned u; } v; v.f = f;
    unsigned u = v.u;
    unsigned r = (u + 0x7fffu + ((u >> 16) & 1u)) >> 16;
    return (unsigned short)r;
}
__device__ __forceinline__ float4v mfma16(short8 a, short8 b, float4v c) {
    return __builtin_amdgcn_mfma_f32_16x16x32_bf16(a, b, c, 0, 0, 0);
}
// Async global->LDS, 16B per lane. LDS dest = wave-uniform ptr + lane*16.
__device__ __forceinline__ void g2lds16(const void* g, void* l) {
    __builtin_amdgcn_global_load_lds(
        (const __attribute__((address_space(1))) unsigned int*)g,
        (__attribute__((address_space(3))) unsigned int*)l, 16, 0, 0);
}
// Pack high-halves of (a,b) with +0x8000 rounding into one dword [b_hi:a_hi].
__device__ __forceinline__ unsigned pk2bf(float a, float b) {
    union { float f; unsigned u; } x, y; x.f = a; y.f = b;
    return __builtin_amdgcn_perm(y.u + 0x8000u, x.u + 0x8000u, 0x07060302u);
}

// ---------------------------------------------------------------------------
// Prep (fused): [blocks 0..CVT_BLOCKS) convert x fp32->bf16 (8 elems/thread);
// remaining blocks pack W^T bf16 + fp64-accurate RoPE tables.
// ---------------------------------------------------------------------------
__global__ void prep_kernel(const float* __restrict__ x, unsigned short* __restrict__ xb,
                            const float* __restrict__ Wq, const float* __restrict__ Wk,
                            const float* __restrict__ Wv, const float* __restrict__ Wo,
                            unsigned short* __restrict__ WqkvT, unsigned short* __restrict__ WoT,
                            float* __restrict__ cosT, float* __restrict__ sinT) {
    if (blockIdx.x < CVT_BLOCKS) {
        size_t e = ((size_t)blockIdx.x * 256 + threadIdx.x) * 8;
        const float4* p = (const float4*)(x + e);
        float4 v0 = p[0], v1 = p[1];
        short8 w;
        w[0]=(short)f2b(v0.x); w[1]=(short)f2b(v0.y); w[2]=(short)f2b(v0.z); w[3]=(short)f2b(v0.w);
        w[4]=(short)f2b(v1.x); w[5]=(short)f2b(v1.y); w[6]=(short)f2b(v1.z); w[7]=(short)f2b(v1.w);
        *(short8*)(xb + e) = w;
        return;
    }
    int idx = (blockIdx.x - CVT_BLOCKS) * 256 + threadIdx.x;
    const int N1 = QKVW * CC;          // 131072
    const int N2 = N1 + CC * CC;       // +65536
    const int N3 = N2 + TT * 32;       // +12288
    if (idx < N1) {
        int n = idx >> 8, k = idx & 255;
        float w;
        if (n < 256)      w = Wq[k * 256 + n];
        else if (n < 384) w = Wk[k * 128 + (n - 256)];
        else              w = Wv[k * 128 + (n - 384)];
        WqkvT[n * 256 + k] = f2b(w);
    } else if (idx < N2) {
        int i = idx - N1; int n = i >> 8, k = i & 255;
        WoT[n * 256 + k] = f2b(Wo[k * 256 + n]);
    } else if (idx < N3) {
        int i = idx - N2;
        int t = i >> 5, f = i & 31;
        double invf = exp2(-(double)f / 32.0 * 13.287712379549449);  // 10000^(-f/32)
        double ang = (double)t * invf;
        cosT[t * 32 + f] = (float)cos(ang);
        sinT[t * 32 + f] = (float)sin(ang);
    }
}

// ---------------------------------------------------------------------------
// GEMM1 (m97-style): qkv = xb @ [Wq|Wk|Wv], async LDS staging, fused RoPE +
// layout epilogue. XCD swizzle: the 4 nt-variants of one mt share an XCD.
// Emits: Qr [b][h][t][64] (*0.125*log2e), Kr [b][g][s][64],
//        Vt [b][g][s/64][d][sigma(s%64)]  (sigma = attn's P-column permute).
// ---------------------------------------------------------------------------
__global__ __launch_bounds__(256) void gemm_qkv_kernel(
    const unsigned short* __restrict__ A, const unsigned short* __restrict__ BT,
    unsigned short* __restrict__ Qr, unsigned short* __restrict__ Kr,
    unsigned short* __restrict__ Vt,
    const float* __restrict__ cosT, const float* __restrict__ sinT)
{
    __shared__ __align__(16) unsigned short As[128 * 32];
    __shared__ __align__(16) unsigned short Bs[128 * 32];
    const int tid  = threadIdx.x;
    const int lane = tid & 63;
    const int quad = lane >> 4, l16 = lane & 15;
    const int wave = tid >> 6;
    const int mt = ((blockIdx.x >> 5) << 3) | (blockIdx.x & 7);
    const int nt = (blockIdx.x >> 3) & 3;
    const int mbase = mt * 128, nbase = nt * 128;
    const int wmb = (wave >> 1) * 64, wnb = (wave & 1) * 64;

    float4v acc[4][4] = {};
    const int r0 = tid >> 2, kc = (tid & 3) * 8;
    const int ldsW = (tid & ~63) * 16;
    const unsigned short* gA0 = A  + (size_t)(mbase + r0) * CC + kc;
    const unsigned short* gB0 = BT + (size_t)(nbase + r0) * CC + kc;

    for (int kt = 0; kt < CC; kt += 32) {
        __syncthreads();
        g2lds16(gA0 + kt,                  (char*)As + ldsW);
        g2lds16(gA0 + kt + (size_t)64*CC,  (char*)As + 4096 + ldsW);
        g2lds16(gB0 + kt,                  (char*)Bs + ldsW);
        g2lds16(gB0 + kt + (size_t)64*CC,  (char*)Bs + 4096 + ldsW);
        __syncthreads();

        short8 af[4], bf_[4];
        #pragma unroll
        for (int i = 0; i < 4; i++)
            af[i] = *(const short8*)&As[(wmb + i * 16 + l16) * 32 + quad * 8];
        #pragma unroll
        for (int i = 0; i < 4; i++)
            bf_[i] = *(const short8*)&Bs[(wnb + i * 16 + l16) * 32 + quad * 8];
        #pragma unroll
        for (int i = 0; i < 4; i++)
            #pragma unroll
            for (int j = 0; j < 4; j++)
                acc[i][j] = mfma16(af[i], bf_[j], acc[i][j]);
    }

    const int gn0 = nbase + wnb;
    const int gm0 = mbase + wmb;
    if (gn0 < 384) {
        const bool isq = (gn0 < 256);
        const int  hh  = isq ? (gn0 >> 6) : ((gn0 - 256) >> 6);
        const float qs = isq ? 0.18033688011112042f : 1.0f;   // 0.125 * log2(e)
        #pragma unroll
        for (int i = 0; i < 4; i++) {
            #pragma unroll
            for (int r = 0; r < 4; r++) {
                int gm = gm0 + i * 16 + quad * 4 + r;
                int b = gm / TT, t = gm - b * TT;
                unsigned short* dst = isq
                    ? (Qr + (((size_t)b * HH  + hh) * TT + t) * 64)
                    : (Kr + (((size_t)b * KVH + hh) * TT + t) * 64);
                #pragma unroll
                for (int j = 0; j < 2; j++) {
                    int f = j * 16 + l16;
                    float cs = cosT[t * 32 + f], sn = sinT[t * 32 + f];
                    float a  = acc[i][j][r],     c2 = acc[i][j + 2][r];
                    dst[f]      = f2b((a * cs - c2 * sn) * qs);
                    dst[f + 32] = f2b((c2 * cs + a * sn) * qs);
                }
            }
        }
    } else {
        const int g = (gn0 - 384) >> 6;
        #pragma unroll
        for (int i = 0; i < 4; i++) {
            #pragma unroll
            for (int r = 0; r < 4; r++) {
                int gm = gm0 + i * 16 + quad * 4 + r;
                int b = gm / TT, s = gm - b * TT;
                int s6 = s & 63;
                int sig = (s6 & 15) * 4 + (s6 >> 4);   // key permutation
                unsigned short* dst = Vt + (((size_t)b * KVH + g) * 6 + (s >> 6)) * 4096 + sig;
                #pragma unroll
                for (int j = 0; j < 4; j++)
                    dst[(j * 16 + l16) * 64] = f2b(acc[i][j][r]);
            }
        }
    }
}

// ---------------------------------------------------------------------------
// GEMM2 (m97-style): out = y @ Wo, out fp32. XCD swizzle on (mt,nt).
// ---------------------------------------------------------------------------
__global__ __launch_bounds__(256) void gemm_out_kernel(
    const unsigned short* __restrict__ A, const unsigned short* __restrict__ BT,
    float* __restrict__ C)
{
    __shared__ __align__(16) unsigned short As[128 * 32];
    __shared__ __align__(16) unsigned short Bs[128 * 32];
    const int tid  = threadIdx.x;
    const int lane = tid & 63;
    const int quad = lane >> 4, l16 = lane & 15;
    const int wave = tid >> 6;
    const int mt = ((blockIdx.x >> 4) << 3) | (blockIdx.x & 7);
    const int nt = (blockIdx.x >> 3) & 1;
    const int mbase = mt * 128, nbase = nt * 128;
    const int wmb = (wave >> 1) * 64, wnb = (wave & 1) * 64;

    float4v acc[4][4] = {};
    const int r0 = tid >> 2, kc = (tid & 3) * 8;
    const int ldsW = (tid & ~63) * 16;
    const unsigned short* gA0 = A  + (size_t)(mbase + r0) * CC + kc;
    const unsigned short* gB0 = BT + (size_t)(nbase + r0) * CC + kc;

    for (int kt = 0; kt < CC; kt += 32) {
        __syncthreads();
        g2lds16(gA0 + kt,                  (char*)As + ldsW);
        g2lds16(gA0 + kt + (size_t)64*CC,  (char*)As + 4096 + ldsW);
        g2lds16(gB0 + kt,                  (char*)Bs + ldsW);
        g2lds16(gB0 + kt + (size_t)64*CC,  (char*)Bs + 4096 + ldsW);
        __syncthreads();

        short8 af[4], bf_[4];
        #pragma unroll
        for (int i = 0; i < 4; i++)
            af[i] = *(const short8*)&As[(wmb + i * 16 + l16) * 32 + quad * 8];
        #pragma unroll
        for (int i = 0; i < 4; i++)
            bf_[i] = *(const short8*)&Bs[(wnb + i * 16 + l16) * 32 + quad * 8];
        #pragma unroll
        for (int i = 0; i < 4; i++)
            #pragma unroll
            for (int j = 0; j < 4; j++)
                acc[i][j] = mfma16(af[i], bf_[j], acc[i][j]);
    }
    #pragma unroll
    for (int i = 0; i < 4; i++)
        #pragma unroll
        for (int j = 0; j < 4; j++)
            #pragma unroll
            for (int r = 0; r < 4; r++)
                C[(size_t)(mbase + wmb + i * 16 + quad * 4 + r) * CC + nbase + wnb + j * 16 + l16]
                    = acc[i][j][r];
}

// ---------------------------------------------------------------------------
// Attention v4: block = (b, g, p) computes q-tile p fully (kt=0..p), writes
// it, then q-tile 5-p (kt=0..5-p): (p+1)+(6-p)=7 stages for EVERY block
// (perfect balance), with only ONE acc/accl/qf set live (no spill; R4's
// concurrent-2-tile version spilled: WRITE_SIZE 128MB of scratch traffic).
// K/V double-buffered, stage stream continuous across the tile switch.
// P stored via key-permutation sigma (lane's 4 score cols contiguous ->
// ds_write_b64). Fixed-max softmax; row-sums via ones-MFMA. No shuffles.
// ---------------------------------------------------------------------------
__global__ __launch_bounds__(256, 3) void attn_kernel(
    const unsigned short* __restrict__ Qr, const unsigned short* __restrict__ Kr,
    const unsigned short* __restrict__ Vt, unsigned short* __restrict__ y)
{
    __shared__ __align__(16) unsigned short Ks[2][64 * 64];  // 2 x 8 KB, XOR-swizzled [s][d]
    __shared__ __align__(16) unsigned short Vs[2][64 * 64];  // 2 x 8 KB, XOR-swizzled [d][sigma]
    __shared__ __align__(16) unsigned short Ps[4][32 * 64];  // per-wave [q][sigma], row-XOR

    const int tid  = threadIdx.x;
    const int lane = tid & 63;
    const int wave = tid >> 6;
    const int quad = lane >> 4, l16 = lane & 15;

    // decode with XCD co-location: all 3 p-blocks of (b,g) share bid&7
    const int xc  = blockIdx.x & 7;
    const int jj  = blockIdx.x >> 3;        // 0..95
    const int p   = jj % 3;
    const int bg  = (jj / 3) * 8 + xc;      // 0..255
    const int g   = bg & 1, b = bg >> 1;
    const int h   = g * 2 + (wave >> 1);

    const unsigned short* Kbase = Kr + ((size_t)b * KVH + g) * TT * 64;
    const unsigned short* Vbase = Vt + ((size_t)b * KVH + g) * 6 * 4096;
    const unsigned short* Qbase = Qr + ((size_t)b * HH + h) * TT * 64;
    unsigned short* ybase = y + (size_t)b * TT * CC + h * 64;
    char* Pw = (char*)&Ps[wave][0];
    const int ldsWave = (tid & ~63) * 16;
    int gc0, gc1;
    { int L0 = tid;       gc0 = ((L0 & ~7) | ((L0 & 7) ^ ((L0 >> 3) & 7))) * 8;
      int L1 = 256 + tid; gc1 = ((L1 & ~7) | ((L1 & 7) ^ ((L1 >> 3) & 7))) * 8; }

    auto stage = [&](int bi, int kt) {
        const unsigned short* kB = Kbase + (size_t)kt * 4096;
        const unsigned short* vB = Vbase + (size_t)kt * 4096;
        g2lds16(kB + gc0, (char*)&Ks[bi][0] + ldsWave);
        g2lds16(kB + gc1, (char*)&Ks[bi][0] + 4096 + ldsWave);
        g2lds16(vB + gc0, (char*)&Vs[bi][0] + ldsWave);
        g2lds16(vB + gc1, (char*)&Vs[bi][0] + 4096 + ldsWave);
    };

    short8 ones;
    #pragma unroll
    for (int j = 0; j < 8; j++) ones[j] = (short)0x3F80;   // bf16 1.0

    int seq = 0;          // global stage counter -> buffer parity
    stage(0, 0);

    for (int tph = 0; tph < 2; tph++) {
        const int qt = tph ? (5 - p) : p;
        const int qb = qt * 64 + (wave & 1) * 32;   // this wave's 32 q-rows

        // Q fragments (A-layout): m = l16, k = half*32 + quad*8
        short8 qf[2][2];
        #pragma unroll
        for (int mi = 0; mi < 2; mi++)
            #pragma unroll
            for (int half = 0; half < 2; half++)
                qf[mi][half] = *(const short8*)(Qbase
                    + (size_t)(qb + mi * 16 + l16) * 64 + half * 32 + quad * 8);

        float4v acc[2][4] = {};
        float4v accl[2]   = {};

        for (int kt = 0; kt <= qt; kt++) {
            __syncthreads();   // drains staging of current seq; fences prior readers
            // prefetch next stage in the continuous sequence (overlaps compute)
            if (kt < qt)        stage((seq + 1) & 1, kt + 1);
            else if (tph == 0)  stage((seq + 1) & 1, 0);
            const unsigned short* Kc = &Ks[seq & 1][0];
            const unsigned short* Vc = &Vs[seq & 1][0];

            // ---- S = Q . K^T (16 MFMAs) ----
            float4v s_[2][4];
            #pragma unroll
            for (int js = 0; js < 4; js++) {
                int srow = js * 16 + l16, sw = srow & 7;
                short8 kb0 = *(const short8*)((const char*)Kc + srow * 128 + ((quad ^ sw) * 16));
                short8 kb1 = *(const short8*)((const char*)Kc + srow * 128 + (((4 + quad) ^ sw) * 16));
                #pragma unroll
                for (int mi = 0; mi < 2; mi++) {
                    float4v z = {};
                    z = mfma16(qf[mi][0], kb0, z);
                    s_[mi][js] = mfma16(qf[mi][1], kb1, z);
                }
            }

            // ---- causal mask (diagonal tile only) ----
            if (kt == qt) {
                #pragma unroll
                for (int mi = 0; mi < 2; mi++)
                    #pragma unroll
                    for (int js = 0; js < 4; js++) {
                        int coll = js * 16 + l16;
                        #pragma unroll
                        for (int r = 0; r < 4; r++) {
                            int rowl = (wave & 1) * 32 + mi * 16 + quad * 4 + r;
                            if (coll > rowl) s_[mi][js][r] = -1e30f;
                        }
                    }
            }

            // ---- P = exp2(s), packed b64 store (sigma makes 4 cols contiguous) ----
            #pragma unroll
            for (int mi = 0; mi < 2; mi++)
                #pragma unroll
                for (int r = 0; r < 4; r++) {
                    float e0 = __builtin_amdgcn_exp2f(s_[mi][0][r]);
                    float e1 = __builtin_amdgcn_exp2f(s_[mi][1][r]);
                    float e2 = __builtin_amdgcn_exp2f(s_[mi][2][r]);
                    float e3 = __builtin_amdgcn_exp2f(s_[mi][3][r]);
                    unsigned long long d =
                        (unsigned long long)pk2bf(e0, e1) |
                        ((unsigned long long)pk2bf(e2, e3) << 32);
                    int rho = mi * 16 + quad * 4 + r;
                    int ch  = l16 ^ (((quad * 4 + r) & 7) << 1);
                    *(unsigned long long*)(Pw + rho * 128 + ch * 8) = d;
                }

            // ---- P A-frags (b128) + PV (16 MFMAs) + row-sums (4 MFMAs) ----
            short8 pa[2][2];
            #pragma unroll
            for (int mi = 0; mi < 2; mi++)
                #pragma unroll
                for (int half = 0; half < 2; half++) {
                    int chp = (2 * (half * 4 + quad)) ^ ((l16 & 7) << 1);
                    pa[mi][half] = *(const short8*)(Pw + (mi * 16 + l16) * 128 + chp * 8);
                }
            #pragma unroll
            for (int dj = 0; dj < 4; dj++) {
                int vrow = dj * 16 + l16, sw = vrow & 7;
                short8 vb0 = *(const short8*)((const char*)Vc + vrow * 128 + ((quad ^ sw) * 16));
                short8 vb1 = *(const short8*)((const char*)Vc + vrow * 128 + (((4 + quad) ^ sw) * 16));
                #pragma unroll
                for (int mi = 0; mi < 2; mi++) {
                    acc[mi][dj] = mfma16(pa[mi][0], vb0, acc[mi][dj]);
                    acc[mi][dj] = mfma16(pa[mi][1], vb1, acc[mi][dj]);
                }
            }
            #pragma unroll
            for (int mi = 0; mi < 2; mi++) {
                accl[mi] = mfma16(pa[mi][0], ones, accl[mi]);
                accl[mi] = mfma16(pa[mi][1], ones, accl[mi]);
            }
            seq++;
        }

        // ---- epilogue for this q-tile: y[b][t][h*64+d] = acc / l ----
        #pragma unroll
        for (int mi = 0; mi < 2; mi++) {
            float rinv[4];
            #pragma unroll
            for (int r = 0; r < 4; r++) rinv[r] = 1.0f / accl[mi][r];
            #pragma unroll
            for (int dj = 0; dj < 4; dj++)
                #pragma unroll
                for (int r = 0; r < 4; r++) {
                    int tt = qb + mi * 16 + quad * 4 + r;
                    ybase[(size_t)tt * CC + dj * 16 + l16] = f2b(acc[mi][dj][r] * rinv[r]);
                }
        }
    }
}

// ---------------------------------------------------------------------------
extern "C" void kernel_launch(void* const* d_in, const int* in_sizes, int n_in,
                              void* d_out, int out_size, void* d_ws, size_t ws_size,
                              hipStream_t stream) {
    const float* x  = (const float*)d_in[0];
    const float* Wq = (const float*)d_in[1];
    const float* Wk = (const float*)d_in[2];
    const float* Wv = (const float*)d_in[3];
    const float* Wo = (const float*)d_in[4];
    float* out = (float*)d_out;

    char* ws = (char*)d_ws;
    size_t off = 0;
    unsigned short* xb = (unsigned short*)(ws + off); off += (size_t)MROWS * CC * 2;
    unsigned short* Qr = (unsigned short*)(ws + off); off += (size_t)BB * HH  * TT * 64 * 2;
    unsigned short* Kr = (unsigned short*)(ws + off); off += (size_t)BB * KVH * TT * 64 * 2;
    unsigned short* Vt = (unsigned short*)(ws + off); off += (size_t)BB * KVH * TT * 64 * 2;
    unsigned short* y  = (unsigned short*)(ws + off); off += (size_t)MROWS * CC * 2;
    unsigned short* WqkvT = (unsigned short*)(ws + off); off += (size_t)QKVW * CC * 2;
    unsigned short* WoT   = (unsigned short*)(ws + off); off += (size_t)CC * CC * 2;
    float* cosT = (float*)(ws + off); off += (size_t)TT * 32 * 4;
    float* sinT = (float*)(ws + off); off += (size_t)TT * 32 * 4;

    prep_kernel<<<CVT_BLOCKS + 816, 256, 0, stream>>>(x, xb, Wq, Wk, Wv, Wo,
                                                      WqkvT, WoT, cosT, sinT);
    gemm_qkv_kernel<<<(MROWS / 128) * 4, 256, 0, stream>>>(xb, WqkvT, Qr, Kr, Vt, cosT, sinT);
    attn_kernel<<<BB * KVH * 3, 256, 0, stream>>>(Qr, Kr, Vt, y);
    gemm_out_kernel<<<(MROWS / 128) * 2, 256, 0, stream>>>(y, WoT, out);
}